// Round 9
// baseline (442.098 us; speedup 1.0000x reference)
//
#include <hip/hip_runtime.h>

constexpr int K  = 128;  // states
constexpr int T  = 512;  // timesteps
constexpr int NB = 16;   // batch columns per block/wave
constexpr int CH = 8;    // eh chunk (timesteps) per DMA buffer

typedef __attribute__((ext_vector_type(8))) int   int8v;  // f8f6f4 A/B operand
typedef __attribute__((ext_vector_type(4))) float f32x4;  // mfma C/D

__device__ __forceinline__ void wait_vm0() {
  asm volatile("s_waitcnt vmcnt(0)" ::: "memory");
}
// async global -> LDS, 16B/lane; LDS dest = wave-uniform base + lane*16
__device__ __forceinline__ void dma16(const void* g, void* l) {
  __builtin_amdgcn_global_load_lds(
      (const __attribute__((address_space(1))) void*)g,
      (__attribute__((address_space(3))) void*)l, 16, 0, 0);
}
// pack two fp32 -> bf16x2 (round-half-up)
__device__ __forceinline__ unsigned bfpair(float a, float b) {
  unsigned ua = __float_as_uint(a) + 0x8000u;
  unsigned ub = __float_as_uint(b) + 0x8000u;
  return (ua >> 16) | (ub & 0xFFFF0000u);
}
__device__ __forceinline__ float lo16(int w) { return __uint_as_float((unsigned)w << 16); }
__device__ __forceinline__ float hi16(int w) { return __uint_as_float((unsigned)w & 0xFFFF0000u); }

// ---- pre-pass 1: len[b] = sum(mask[b,:]) ----
__global__ __launch_bounds__(64, 1)
void len_kern(const float* __restrict__ mask, int* __restrict__ len) {
  const int b = blockIdx.x, l = threadIdx.x;
  const float4* mp = reinterpret_cast<const float4*>(mask + (size_t)b * T) + l * 2;
  float4 v0 = mp[0], v1 = mp[1];
  float s = (v0.x + v0.y) + (v0.z + v0.w) + (v1.x + v1.y) + (v1.z + v1.w);
  #pragma unroll
  for (int o = 32; o; o >>= 1) s += __shfl_xor(s, o);
  if (l == 0) len[b] = (int)(s + 0.5f);
}

// ---- pre-pass 2: eh = exp(h) as bf16, laid out DMA-ready for the main wave.
// out short idx: ((g*512+t)*4 + d)*512 + lane*8 + i ; lane=(q,b)=16q+b ;
// value i -> j = 32d + 16*(i>>2) + 4q + (i&3), batch row g*16+b.
__global__ __launch_bounds__(256, 1)
void eh_kern(const float* __restrict__ h, unsigned short* __restrict__ ehp) {
  const int g = blockIdx.x >> 9, t = blockIdx.x & 511;
  const int d = threadIdx.x >> 6, lane = threadIdx.x & 63;
  const int q = lane >> 4, b = lane & 15;
  const float* hp = h + ((size_t)(g * NB + b) * T + t) * K + 32 * d + 4 * q;
  float4 x = *reinterpret_cast<const float4*>(hp);        // j = 32d+4q+r
  float4 y = *reinterpret_cast<const float4*>(hp + 16);   // j = 32d+16+4q+r
  int4 o;
  o.x = (int)bfpair(__expf(x.x), __expf(x.y));
  o.y = (int)bfpair(__expf(x.z), __expf(x.w));
  o.z = (int)bfpair(__expf(y.x), __expf(y.y));
  o.w = (int)bfpair(__expf(y.z), __expf(y.w));
  *reinterpret_cast<int4*>(ehp + ((size_t)blockIdx.x * 4 + d) * 512 + lane * 8) = o;
}

// ---- main: 16 blocks x 1 wave. Barrier-free. Per step:
//   C_s(16x16) = E_s(fp8) @ P(bf8, K=128) via ONE scaled mfma per strip s=0..7
//   P'[j,b] = C*eh*exp(Scur - Snxt), freeze per column at len_b.
// P single-buffered in LDS (intra-wave DS ordering). Tracker state j=2, bias 3.
__global__ __launch_bounds__(64, 1)
void crf_fwd(const unsigned short* __restrict__ ehp, const int* __restrict__ len,
             const float* __restrict__ trans, float* __restrict__ out) {
  const int lane = threadIdx.x;      // = 16q + b
  const int q = lane >> 4, b = lane & 15;
  const int g = blockIdx.x, boff = g * NB;

  __shared__ short ehb[2][CH][4][512];                  // 64 KB eh staging
  __shared__ __align__(16) unsigned char P[64 * 48];    // bf8 B-frags, pad-48

  // ---- A fragments: A[s] = fp8(exp(trans[16s + b][32q + i])), i = 0..31 ----
  int8v A[8];
  #pragma unroll
  for (int s = 0; s < 8; ++s) {
    const float4* rp = reinterpret_cast<const float4*>(
        trans + (size_t)(16 * s + b) * K + 32 * q);
    int w[8];
    #pragma unroll
    for (int e = 0; e < 8; ++e) {
      float4 v = rp[e];
      int t0 = __builtin_amdgcn_cvt_pk_fp8_f32(__expf(v.x), __expf(v.y), 0, false);
      w[e]   = __builtin_amdgcn_cvt_pk_fp8_f32(__expf(v.z), __expf(v.w), t0, true);
    }
    A[s] = (int8v){w[0], w[1], w[2], w[3], w[4], w[5], w[6], w[7]};
  }

  // ---- init P: zero, then SOS one-hot (bf8 1.0 = 0x3C at k=0, col b) ----
  {
    int4 z = {0, 0, 0, 0};
    *reinterpret_cast<int4*>(P + lane * 48)      = z;
    *reinterpret_cast<int4*>(P + lane * 48 + 16) = z;
    *reinterpret_cast<int4*>(P + lane * 48 + 32) = z;
    if (lane < 16) P[lane * 48] = 0x3C;
  }

  const int lenv = len[boff + b];
  int tmax = lenv;
  #pragma unroll
  for (int o = 1; o < 64; o <<= 1) tmax = max(tmax, __shfl_xor(tmax, o));

  // ---- first eh chunk ----
#define ISSUE(t0, buf)                                                        \
  { _Pragma("unroll") for (int r_ = 0; r_ < CH; ++r_) {                       \
      _Pragma("unroll") for (int d_ = 0; d_ < 4; ++d_)                        \
        dma16(ehp + ((size_t)(g * 512 + (t0) + r_) * 4 + d_) * 512 + lane * 8,\
              &ehb[buf][r_][d_][0]); } }
  ISSUE(0, 0)

  float Scur = 0.0f, Snxt = 3.0f;   // shifts (valid in lanes 0..15, b = lane)
  int cur = 0;

  for (int t = 0; t < tmax; ++t) {
    const int cpos = t & (CH - 1);
    if (cpos == 0) {
      wait_vm0();
      cur = (t >> 3) & 1;
      if (t + CH < tmax) ISSUE(t + CH, cur ^ 1)
    }

    // es broadcast: lane b's exp(Scur - Snxt) to all its q-lanes
    const float es = __int_as_float(__builtin_amdgcn_ds_bpermute(
        b * 4, __float_as_int(__expf(Scur - Snxt))));

    // B operand: this lane's 32 bf8 (k = 32q..32q+31, col b)
    int4 B0 = *reinterpret_cast<const int4*>(P + lane * 48);
    int4 B1 = *reinterpret_cast<const int4*>(P + lane * 48 + 16);
    int8v Bv = (int8v){B0.x, B0.y, B0.z, B0.w, B1.x, B1.y, B1.z, B1.w};

    // eh for this step: 4 x b128 (bf16x8 each)
    int4 E0 = *reinterpret_cast<const int4*>(&ehb[cur][cpos][0][lane * 8]);
    int4 E1 = *reinterpret_cast<const int4*>(&ehb[cur][cpos][1][lane * 8]);
    int4 E2 = *reinterpret_cast<const int4*>(&ehb[cur][cpos][2][lane * 8]);
    int4 E3 = *reinterpret_cast<const int4*>(&ehb[cur][cpos][3][lane * 8]);

    f32x4 C[8];
    #pragma unroll
    for (int s = 0; s < 8; ++s)
      C[s] = __builtin_amdgcn_mfma_scale_f32_16x16x128_f8f6f4(
          A[s], Bv, (f32x4){0.f, 0.f, 0.f, 0.f},
          0 /*A=fp8*/, 1 /*B=bf8*/, 0, 0x7F7F7F7F, 0, 0x7F7F7F7F);

    const bool act = (t < lenv);
    float eh2 = 0.f;   // eh at (d=0, idx=2): j = 4q+2 -> row 2 for q=0 lanes

    #pragma unroll
    for (int s = 0; s < 8; ++s) {
      const int4 Ed = (s >> 1) == 0 ? E0 : (s >> 1) == 1 ? E1 : (s >> 1) == 2 ? E2 : E3;
      float f0, f1, f2, f3;
      if ((s & 1) == 0) { f0 = lo16(Ed.x); f1 = hi16(Ed.x); f2 = lo16(Ed.y); f3 = hi16(Ed.y); }
      else              { f0 = lo16(Ed.z); f1 = hi16(Ed.z); f2 = lo16(Ed.w); f3 = hi16(Ed.w); }
      if (s == 0) eh2 = f2;
      float m0 = C[s][0] * f0 * es, m1 = C[s][1] * f1 * es;
      float m2 = C[s][2] * f2 * es, m3 = C[s][3] * f3 * es;
      int wv = __builtin_amdgcn_cvt_pk_bf8_f32(m0, m1, 0, false);
      wv     = __builtin_amdgcn_cvt_pk_bf8_f32(m2, m3, wv, true);
      if (act)
        *reinterpret_cast<int*>(P + ((s >> 1) * 16 + b) * 48 + 16 * (s & 1) + 4 * q) = wv;
    }

    // tracker: true score of state j=2 (lanes 0..15), bias 3 for bf8 headroom
    const float fs2 = Scur + __logf(C[0][2] * eh2);
    Scur = act ? Snxt : Scur;
    Snxt = act ? (fs2 + 3.0f) : Snxt;
  }
#undef ISSUE

  // ---- epilogue: out[b] = Scur_b + log(sum_j P[j,b] * exp(trans[EOS=1,j])) ----
  const float sig = Scur;
  float acc = 0.f;
  #pragma unroll
  for (int rep = 0; rep < 4; ++rep) {
    const int jg = rep * 4 + q, j0 = jg * 8;
    int2 pw = *reinterpret_cast<const int2*>(P + ((j0 >> 5) * 16 + b) * 48 + (j0 & 31));
    const float* tre = trans + K + j0;
    float4 t0 = *reinterpret_cast<const float4*>(tre);
    float4 t1 = *reinterpret_cast<const float4*>(tre + 4);
    acc += __builtin_amdgcn_cvt_f32_bf8(pw.x, 0) * __expf(t0.x)
         + __builtin_amdgcn_cvt_f32_bf8(pw.x, 1) * __expf(t0.y)
         + __builtin_amdgcn_cvt_f32_bf8(pw.x, 2) * __expf(t0.z)
         + __builtin_amdgcn_cvt_f32_bf8(pw.x, 3) * __expf(t0.w)
         + __builtin_amdgcn_cvt_f32_bf8(pw.y, 0) * __expf(t1.x)
         + __builtin_amdgcn_cvt_f32_bf8(pw.y, 1) * __expf(t1.y)
         + __builtin_amdgcn_cvt_f32_bf8(pw.y, 2) * __expf(t1.z)
         + __builtin_amdgcn_cvt_f32_bf8(pw.y, 3) * __expf(t1.w);
  }
  acc += __shfl_xor(acc, 16);
  acc += __shfl_xor(acc, 32);
  if (lane < 16) out[boff + lane] = sig + __logf(acc);
}

extern "C" void kernel_launch(void* const* d_in, const int* in_sizes, int n_in,
                              void* d_out, int out_size, void* d_ws, size_t ws_size,
                              hipStream_t stream) {
  const float* h     = (const float*)d_in[0];  // (B,T,K) fp32
  const float* trans = (const float*)d_in[1];  // (K,K)   fp32
  const float* mask  = (const float*)d_in[2];  // (B,T)   fp32
  float* out = (float*)d_out;                  // (B,)    fp32
  const int B = in_sizes[0] / (T * K);         // 256

  int* d_len = (int*)d_ws;                                        // 1 KB
  unsigned short* d_eh = (unsigned short*)((char*)d_ws + 1024);   // 32 MB bf16

  len_kern<<<B, 64, 0, stream>>>(mask, d_len);
  eh_kern<<<(B / NB) * T, 256, 0, stream>>>(h, d_eh);
  crf_fwd<<<B / NB, 64, 0, stream>>>(d_eh, d_len, trans, out);
}